// Round 6
// baseline (289.882 us; speedup 1.0000x reference)
//
#include <hip/hip_runtime.h>
#include <stdint.h>

#define NR 8192
#define DIMB 512           // K per row in fp8 bytes
#define BT 128             // block tile M=N=128
#define KT 128             // K per MFMA tile
#define NTILE (DIMB / KT)  // 4
#define SCALE1 0x7F7F7F7F  // 4x e8m0 = 127 -> 2^0 (unit scales)

typedef uint8_t u8;
typedef __attribute__((ext_vector_type(8))) int i32x8;
typedef __attribute__((ext_vector_type(4))) float f32x4;

static __device__ __forceinline__ void gload_lds16(const void* g, void* l) {
    __builtin_amdgcn_global_load_lds(
        (__attribute__((address_space(1))) void*)(void*)g,
        (__attribute__((address_space(3))) void*)l,
        16, 0, 0);
}

static __device__ __forceinline__ i32x8 read32(const u8* pLo, const u8* pHi) {
    int4 lo = *(const int4*)pLo;   // logical k-chunk 2*lk   (k bytes 0..15 of lane span)
    int4 hi = *(const int4*)pHi;   // logical k-chunk 2*lk+1 (k bytes 16..31)
    i32x8 v;
    v[0] = lo.x; v[1] = lo.y; v[2] = lo.z; v[3] = lo.w;
    v[4] = hi.x; v[5] = hi.y; v[6] = hi.z; v[7] = hi.w;
    return v;
}

// One block per row: reciprocal norms, exact fp32 diag term, fp32->fp8(e4m3)
// conversion, and zero rowsum for this call.
__global__ void prep_kernel(const float* __restrict__ xi, const float* __restrict__ xj,
                            u8* __restrict__ xib, u8* __restrict__ xjb,
                            float* __restrict__ inv_ni, float* __restrict__ inv_nj,
                            float* __restrict__ diag, float* __restrict__ rowsum) {
    const int row = blockIdx.x;
    const int t = threadIdx.x;                 // 128 threads, 4 elems each
    const float4 a = ((const float4*)(xi + (size_t)row * 512))[t];
    const float4 b = ((const float4*)(xj + (size_t)row * 512))[t];

    float ssi = a.x*a.x + a.y*a.y + a.z*a.z + a.w*a.w;
    float ssj = b.x*b.x + b.y*b.y + b.z*b.z + b.w*b.w;
    float dot = a.x*b.x + a.y*b.y + a.z*b.z + a.w*b.w;

    int pa = 0, pb = 0;
    pa = __builtin_amdgcn_cvt_pk_fp8_f32(a.x, a.y, pa, false);
    pa = __builtin_amdgcn_cvt_pk_fp8_f32(a.z, a.w, pa, true);
    pb = __builtin_amdgcn_cvt_pk_fp8_f32(b.x, b.y, pb, false);
    pb = __builtin_amdgcn_cvt_pk_fp8_f32(b.z, b.w, pb, true);
    ((int*)(xib + (size_t)row * DIMB))[t] = pa;
    ((int*)(xjb + (size_t)row * DIMB))[t] = pb;

    #pragma unroll
    for (int m = 32; m >= 1; m >>= 1) {
        ssi += __shfl_xor(ssi, m, 64);
        ssj += __shfl_xor(ssj, m, 64);
        dot += __shfl_xor(dot, m, 64);
    }
    __shared__ float red[6];
    const int wave = t >> 6, lane = t & 63;
    if (lane == 0) { red[wave*3+0] = ssi; red[wave*3+1] = ssj; red[wave*3+2] = dot; }
    __syncthreads();
    if (t == 0) {
        float si = red[0] + red[3];
        float sj = red[1] + red[4];
        float d  = red[2] + red[5];
        float ini = rsqrtf(fmaxf(si, 1e-30f));
        float inj = rsqrtf(fmaxf(sj, 1e-30f));
        inv_ni[row] = ini;
        inv_nj[row] = inj;
        diag[row] = d * ini * inj;   // exact-fp32 matched-pair cosine
        rowsum[row] = 0.0f;
    }
}

// Fused NT-GEMM + exp + row-sum. MX-fp8 (unit scales), m148/m97 recipe:
// 128x128 tile, 4 waves (2x2, 64x64 wave tile), KT=128 per MFMA, 32 KB LDS
// single-buffered, simple stage->barrier->compute loop; latency hidden by
// 3 blocks/CU TLP (not explicit pipelining). XOR chunk-swizzle (c ^= row&7)
// on 16B chunks of the 128B rows -> perfect 2-way (free) on ds_read_b128.
__global__ __launch_bounds__(256, 3)
void gemm_rowsum(const u8* __restrict__ A8, const u8* __restrict__ B8,
                 const float* __restrict__ inv_ni, const float* __restrict__ inv_nj,
                 float* __restrict__ rowsum) {
    __shared__ __align__(16) u8 ldsA[BT * KT];   // 16 KB
    __shared__ __align__(16) u8 ldsB[BT * KT];   // 16 KB

    const int tid = threadIdx.x;
    // XCD-aware, L2-aware: xcd owns 8 row-panels; concurrent ~96 blocks/XCD
    // cover 8 row-panels x ~12 col-panels: A 512KB + B ~768KB << 4MB L2.
    const int orig = blockIdx.x;
    const int xcd = orig & 7, kk = orig >> 3;     // kk in 0..511
    const int by = xcd * 8 + (kk & 7);            // 0..63
    const int bx = kk >> 3;                       // 0..63
    const int row0 = by * BT, col0 = bx * BT;

    // ---- staging: thread t covers slots {t + i*256}, slot = row*8 + chunk ----
    // row = (t>>3) + i*32 (row&7 invariant in i), phys chunk = t&7.
    // Inverse swizzle: fetch logical chunk (t&7) ^ (row&7) from global.
    const int r0 = tid >> 3;                      // 0..31
    const int lc = (tid & 7) ^ (r0 & 7);          // logical 16B k-chunk
    const u8* gA = A8 + (size_t)(row0 + r0) * DIMB + lc * 16;
    const u8* gB = B8 + (size_t)(col0 + r0) * DIMB + lc * 16;
    u8* const dA = ldsA + tid * 16;
    u8* const dB = ldsB + tid * 16;

    // ---- fragment reads: lane l -> row (l&15), k-span (l>>4)*32 (2 chunks) ----
    const int lane = tid & 63;
    const int lr = lane & 15, lk = lane >> 4;
    const int wid = tid >> 6;
    const int wm = wid >> 1, wn = wid & 1;        // 2x2 waves, 64x64 each
    const int swz = lr & 7;
    const int cLo = ((lk * 2) ^ swz) * 16;        // phys byte of logical chunk 2lk
    const int cHi = ((lk * 2 + 1) ^ swz) * 16;
    const u8* const aLo = ldsA + (wm * 64 + lr) * 128 + cLo;  // +m*2048 per frag
    const u8* const aHi = ldsA + (wm * 64 + lr) * 128 + cHi;
    const u8* const bLo = ldsB + (wn * 64 + lr) * 128 + cLo;  // +n*2048 per frag
    const u8* const bHi = ldsB + (wn * 64 + lr) * 128 + cHi;

    f32x4 acc[4][4] = {};

    #pragma unroll
    for (int t = 0; t < NTILE; ++t) {
        if (t) __syncthreads();               // prev tile's reads complete
        #pragma unroll
        for (int i = 0; i < 4; ++i) {         // 8 x global_load_lds_dwordx4
            gload_lds16(gA + t * KT + i * 32 * DIMB, dA + i * 4096);
            gload_lds16(gB + t * KT + i * 32 * DIMB, dB + i * 4096);
        }
        asm volatile("s_waitcnt vmcnt(0)" ::: "memory");
        __syncthreads();

        i32x8 af[4];
        #pragma unroll
        for (int m = 0; m < 4; ++m)
            af[m] = read32(aLo + m * 2048, aHi + m * 2048);
        #pragma unroll
        for (int n = 0; n < 4; ++n) {
            const i32x8 bg = read32(bLo + n * 2048, bHi + n * 2048);
            #pragma unroll
            for (int m = 0; m < 4; ++m)
                acc[m][n] = __builtin_amdgcn_mfma_scale_f32_16x16x128_f8f6f4(
                    af[m], bg, acc[m][n], 0 /*cbsz: fp8*/, 0 /*blgp: fp8*/,
                    0, SCALE1, 0, SCALE1);
        }
    }

    // ---- epilogue: cosine scale, exp, row-reduce, one atomic per row ----
    float inj[4];
    #pragma unroll
    for (int n = 0; n < 4; ++n)
        inj[n] = inv_nj[col0 + wn * 64 + n * 16 + lr];

    #pragma unroll
    for (int m = 0; m < 4; ++m) {
        #pragma unroll
        for (int e = 0; e < 4; ++e) {
            const int row = row0 + wm * 64 + m * 16 + lk * 4 + e;
            const float in_i = inv_ni[row];
            float s = 0.0f;
            #pragma unroll
            for (int n = 0; n < 4; ++n)
                s += __expf(acc[m][n][e] * in_i * inj[n]);
            s += __shfl_xor(s, 1, 64);
            s += __shfl_xor(s, 2, 64);
            s += __shfl_xor(s, 4, 64);
            s += __shfl_xor(s, 8, 64);
            if (lr == 0)
                atomicAdd(&rowsum[row], s);
        }
    }
}

__global__ void finalize(const float* __restrict__ rowsum,
                         const float* __restrict__ diag,
                         float* __restrict__ out) {
    const float E1 = 2.7182818284590452f;  // exp(1/TAU)
    float acc = 0.0f;
    for (int i = threadIdx.x; i < NR; i += 256)
        acc += __logf(rowsum[i] - E1) - diag[i];
    #pragma unroll
    for (int m = 32; m >= 1; m >>= 1)
        acc += __shfl_xor(acc, m, 64);
    __shared__ float red[4];
    const int wave = threadIdx.x >> 6, lane = threadIdx.x & 63;
    if (lane == 0) red[wave] = acc;
    __syncthreads();
    if (threadIdx.x == 0)
        out[0] = (red[0] + red[1] + red[2] + red[3]) * (1.0f / NR);
}

extern "C" void kernel_launch(void* const* d_in, const int* in_sizes, int n_in,
                              void* d_out, int out_size, void* d_ws, size_t ws_size,
                              hipStream_t stream) {
    const float* xi = (const float*)d_in[0];
    const float* xj = (const float*)d_in[1];

    char* ws = (char*)d_ws;
    u8* xib = (u8*)ws;                                  // 4 MB
    u8* xjb = xib + (size_t)NR * DIMB;                  // 4 MB
    float* inv_ni = (float*)(xjb + (size_t)NR * DIMB);  // 32 KB
    float* inv_nj = inv_ni + NR;
    float* diag   = inv_nj + NR;
    float* rowsum = diag + NR;

    prep_kernel<<<NR, 128, 0, stream>>>(xi, xj, xib, xjb, inv_ni, inv_nj, diag, rowsum);
    gemm_rowsum<<<(NR / BT) * (NR / BT), 256, 0, stream>>>(xib, xjb, inv_ni, inv_nj, rowsum);
    finalize<<<1, 256, 0, stream>>>(rowsum, diag, (float*)d_out);
}

// Round 7
// 113.545 us; speedup vs baseline: 2.5530x; 2.5530x over previous
//
#include <hip/hip_runtime.h>
#include <stdint.h>

#define NR 8192
#define DIM 512
#define BT 128             // block tile M=N
#define BK 64              // K-tile
#define NT (DIM / BK)      // 8 K-tiles

typedef unsigned short u16;
typedef __attribute__((ext_vector_type(8))) __bf16 bf16x8;
typedef __attribute__((ext_vector_type(4))) float f32x4;

static __device__ __forceinline__ u16 f2bf(float f) {
    union { float f; uint32_t u; } v; v.f = f;
    uint32_t u = v.u;
    u += 0x7FFFu + ((u >> 16) & 1u);   // RNE
    return (u16)(u >> 16);
}

static __device__ __forceinline__ void gload_lds16(const void* g, void* l) {
    __builtin_amdgcn_global_load_lds(
        (__attribute__((address_space(1))) void*)(void*)g,
        (__attribute__((address_space(3))) void*)l,
        16, 0, 0);
}

// One block per row: reciprocal norms, exact fp32 diag term, fp32->bf16
// conversion, and zero rowsum for this call.
__global__ void prep_kernel(const float* __restrict__ xi, const float* __restrict__ xj,
                            u16* __restrict__ xib, u16* __restrict__ xjb,
                            float* __restrict__ inv_ni, float* __restrict__ inv_nj,
                            float* __restrict__ diag, float* __restrict__ rowsum) {
    const int row = blockIdx.x;
    const int t = threadIdx.x;                 // 128 threads, 4 elems each
    const float4 a = ((const float4*)(xi + (size_t)row * DIM))[t];
    const float4 b = ((const float4*)(xj + (size_t)row * DIM))[t];

    float ssi = a.x*a.x + a.y*a.y + a.z*a.z + a.w*a.w;
    float ssj = b.x*b.x + b.y*b.y + b.z*b.z + b.w*b.w;
    float dot = a.x*b.x + a.y*b.y + a.z*b.z + a.w*b.w;

    ushort4 av = { f2bf(a.x), f2bf(a.y), f2bf(a.z), f2bf(a.w) };
    ushort4 bv = { f2bf(b.x), f2bf(b.y), f2bf(b.z), f2bf(b.w) };
    ((ushort4*)(xib + (size_t)row * DIM))[t] = av;
    ((ushort4*)(xjb + (size_t)row * DIM))[t] = bv;

    #pragma unroll
    for (int m = 32; m >= 1; m >>= 1) {
        ssi += __shfl_xor(ssi, m, 64);
        ssj += __shfl_xor(ssj, m, 64);
        dot += __shfl_xor(dot, m, 64);
    }
    __shared__ float red[6];
    const int wave = t >> 6, lane = t & 63;
    if (lane == 0) { red[wave*3+0] = ssi; red[wave*3+1] = ssj; red[wave*3+2] = dot; }
    __syncthreads();
    if (t == 0) {
        float si = red[0] + red[3];
        float sj = red[1] + red[4];
        float d  = red[2] + red[5];
        float ini = rsqrtf(fmaxf(si, 1e-30f));
        float inj = rsqrtf(fmaxf(sj, 1e-30f));
        inv_ni[row] = ini;
        inv_nj[row] = inj;
        diag[row] = d * ini * inj;
        rowsum[row] = 0.0f;
    }
}

// Fused NT-GEMM + exp + row-sum. Round-1 structure (simple 2-barrier loop,
// TLP-hidden latency) + conflict-free chunk swizzle + 4 blocks/CU.
// LDS rows are 128B = one bank period; swizzle phys_chunk = c ^ (row&7)
// over the 8 x 16B chunks -> every quarter-wave ds_read_b128 is 2 lanes/bank
// (free, m136). Staging keeps the LDS dest linear and fetches the
// inverse-swizzled global chunk (rule #21).
__global__ __launch_bounds__(256, 4)
void gemm_rowsum(const u16* __restrict__ A, const u16* __restrict__ B,
                 const float* __restrict__ inv_ni, const float* __restrict__ inv_nj,
                 float* __restrict__ rowsum) {
    __shared__ __align__(16) u16 ldsA[BT * BK];   // 16 KB
    __shared__ __align__(16) u16 ldsB[BT * BK];   // 16 KB

    const int tid = threadIdx.x;
    // XCD-aware, L2-aware: xcd owns 8 row-panels; ~128 concurrent blocks/XCD
    // = 8 row-panels x 16 col-panels: A 1MB + B 2MB < 4MB per-XCD L2.
    const int orig = blockIdx.x;
    const int xcd = orig & 7, kidx = orig >> 3;   // kidx 0..511
    const int by = xcd * 8 + (kidx & 7);          // 0..63
    const int bx = kidx >> 3;                     // 0..63
    const int row0 = by * BT, col0 = bx * BT;

    // ---- staging: thread t -> part i row (i*32 + (t>>3)), phys chunk t&7 ----
    // LDS byte = i*4096 + tid*16 (linear); global logical chunk = phys ^ (row&7).
    const int st_row = tid >> 3;                        // 0..31
    const int st_lc  = (tid & 7) ^ (st_row & 7);        // logical 16B k-chunk
    const u16* gA = A + (size_t)(row0 + st_row) * DIM + st_lc * 8;
    const u16* gB = B + (size_t)(col0 + st_row) * DIM + st_lc * 8;
    char* const dA = (char*)ldsA + tid * 16;
    char* const dB = (char*)ldsB + tid * 16;

    // ---- fragment reads (swizzled) ----
    const int lane = tid & 63;
    const int lr = lane & 15, lk = lane >> 4;
    const int wid = tid >> 6;
    const int wm = wid >> 1, wn = wid & 1;              // 2x2 waves, 64x64 tile
    // af[m]: row = wm*64 + m*16 + lr; chunk = kk*4 + lk; phys = chunk ^ (lr&7)
    const int sw = lr & 7;
    const int c0 = (lk ^ sw) * 16;                      // kk=0 phys byte
    const int c1 = ((4 + lk) ^ sw) * 16;                // kk=1 phys byte
    const char* const aR = (const char*)ldsA + (wm * 64 + lr) * 128;
    const char* const bR = (const char*)ldsB + (wn * 64 + lr) * 128;

    f32x4 acc[4][4] = {};

    #pragma unroll 1
    for (int t = 0; t < NT; ++t) {
        if (t) __syncthreads();               // prev tile's reads complete
        #pragma unroll
        for (int i = 0; i < 4; ++i) {         // 8 x global_load_lds_dwordx4
            gload_lds16(gA + t * BK + i * 32 * DIM, dA + i * 4096);
            gload_lds16(gB + t * BK + i * 32 * DIM, dB + i * 4096);
        }
        __syncthreads();                      // drains vmcnt; TLP fills stall

        #pragma unroll
        for (int kk = 0; kk < 2; ++kk) {
            const int cb = kk ? c1 : c0;
            bf16x8 af[4], bg[4];
            #pragma unroll
            for (int m = 0; m < 4; ++m)
                af[m] = *(const bf16x8*)(aR + m * 2048 + cb);
            #pragma unroll
            for (int n = 0; n < 4; ++n)
                bg[n] = *(const bf16x8*)(bR + n * 2048 + cb);
            #pragma unroll
            for (int m = 0; m < 4; ++m)
                #pragma unroll
                for (int n = 0; n < 4; ++n)
                    acc[m][n] = __builtin_amdgcn_mfma_f32_16x16x32_bf16(
                        af[m], bg[n], acc[m][n], 0, 0, 0);
        }
    }

    // ---- epilogue: cosine scale, exp, row-reduce, one atomic per row ----
    float inj[4];
    #pragma unroll
    for (int n = 0; n < 4; ++n)
        inj[n] = inv_nj[col0 + wn * 64 + n * 16 + lr];

    #pragma unroll
    for (int m = 0; m < 4; ++m) {
        #pragma unroll
        for (int e = 0; e < 4; ++e) {
            const int row = row0 + wm * 64 + m * 16 + lk * 4 + e;
            const float in_i = inv_ni[row];
            float s = 0.0f;
            #pragma unroll
            for (int n = 0; n < 4; ++n)
                s += __expf(acc[m][n][e] * in_i * inj[n]);
            s += __shfl_xor(s, 1, 64);
            s += __shfl_xor(s, 2, 64);
            s += __shfl_xor(s, 4, 64);
            s += __shfl_xor(s, 8, 64);
            if (lr == 0)
                atomicAdd(&rowsum[row], s);
        }
    }
}

__global__ void finalize(const float* __restrict__ rowsum,
                         const float* __restrict__ diag,
                         float* __restrict__ out) {
    const float E1 = 2.7182818284590452f;  // exp(1/TAU)
    float acc = 0.0f;
    for (int i = threadIdx.x; i < NR; i += 256)
        acc += __logf(rowsum[i] - E1) - diag[i];
    #pragma unroll
    for (int m = 32; m >= 1; m >>= 1)
        acc += __shfl_xor(acc, m, 64);
    __shared__ float red[4];
    const int wave = threadIdx.x >> 6, lane = threadIdx.x & 63;
    if (lane == 0) red[wave] = acc;
    __syncthreads();
    if (threadIdx.x == 0)
        out[0] = (red[0] + red[1] + red[2] + red[3]) * (1.0f / NR);
}

extern "C" void kernel_launch(void* const* d_in, const int* in_sizes, int n_in,
                              void* d_out, int out_size, void* d_ws, size_t ws_size,
                              hipStream_t stream) {
    const float* xi = (const float*)d_in[0];
    const float* xj = (const float*)d_in[1];

    char* ws = (char*)d_ws;
    u16* xib = (u16*)ws;                                // 8 MB
    u16* xjb = xib + (size_t)NR * DIM;                  // 8 MB
    float* inv_ni = (float*)(xjb + (size_t)NR * DIM);   // 32 KB
    float* inv_nj = inv_ni + NR;
    float* diag   = inv_nj + NR;
    float* rowsum = diag + NR;

    prep_kernel<<<NR, 128, 0, stream>>>(xi, xj, xib, xjb, inv_ni, inv_nj, diag, rowsum);
    gemm_rowsum<<<(NR / BT) * (NR / BT), 256, 0, stream>>>(xib, xjb, inv_ni, inv_nj, rowsum);
    finalize<<<1, 256, 0, stream>>>(rowsum, diag, (float*)d_out);
}